// Round 9
// baseline (130.557 us; speedup 1.0000x reference)
//
#include <hip/hip_runtime.h>
#include <stdint.h>

#define NR 8192
#define DD 128

typedef __attribute__((ext_vector_type(8))) short bf16x8;
typedef __attribute__((ext_vector_type(4))) float f32x4;

#ifdef __has_builtin
#if __has_builtin(__builtin_amdgcn_exp2f)
#define EXP2F __builtin_amdgcn_exp2f
#endif
#endif
#ifndef EXP2F
#define EXP2F exp2f
#endif

// exp(10*x) == exp2(x * 10/ln2).  10/ln2 is folded into the stored bf16:
// nb = round_bf16( sqrt(10/ln2) * normalized ), so every pairwise product
// (MFMA dot, p0 elementwise, diag) is already the exp2 argument.
#define SQK 3.79828255f   // sqrt(10/ln2)

__device__ __forceinline__ uint16_t f2bf_rne(float f) {
  uint32_t u = __float_as_uint(f);
  u += 0x7FFFu + ((u >> 16) & 1u);
  return (uint16_t)(u >> 16);
}
__device__ __forceinline__ float bf2f(uint16_t h) {
  return __uint_as_float(((uint32_t)h) << 16);
}

// ---------------------------------------------------------------------------
// K1: row L2-normalize (fp32), emit bf16 copies scaled by SQK, diag =
// sum(stored^2).  Also zeroes sums and d_out.  One wave per row.
// ---------------------------------------------------------------------------
__global__ __launch_bounds__(256) void k_normalize(
    const float* __restrict__ u1, const float* __restrict__ u2,
    const float* __restrict__ i1, const float* __restrict__ i2,
    uint16_t* __restrict__ nb, float* __restrict__ diag,
    float* __restrict__ sums, float* __restrict__ out)
{
  int tid = threadIdx.x;
  int gid = blockIdx.x * 256 + tid;
  if (gid < 6 * NR) sums[gid] = 0.0f;
  if (gid == 0) out[0] = 0.0f;

  int w = tid >> 6, lane = tid & 63;
  int rowId = blockIdx.x * 4 + w;            // 0..32767
  int mi = rowId >> 13, r = rowId & (NR - 1);
  const float* src = (mi == 0) ? u1 : (mi == 1) ? u2 : (mi == 2) ? i1 : i2;
  const float2 v = *(const float2*)(src + (size_t)r * DD + lane * 2);
  float ss = v.x * v.x + v.y * v.y;
#pragma unroll
  for (int off = 32; off >= 1; off >>= 1) ss += __shfl_xor(ss, off, 64);
  float sc = SQK / fmaxf(sqrtf(ss), 1e-12f);
  uint16_t b0 = f2bf_rne(v.x * sc);
  uint16_t b1 = f2bf_rne(v.y * sc);
  uint16_t* dst = nb + (size_t)mi * NR * DD + (size_t)r * DD + lane * 2;
  *(uint32_t*)dst = (uint32_t)b0 | ((uint32_t)b1 << 16);
  float f0 = bf2f(b0), f1 = bf2f(b1);
  float dd = f0 * f0 + f1 * f1;
#pragma unroll
  for (int off = 32; off >= 1; off >>= 1) dd += __shfl_xor(dd, off, 64);
  if (lane == 0) diag[rowId] = dd;
}

// ---------------------------------------------------------------------------
// K2: Gram row-sums.  Round-8 outer structure (768 blocks, triple-buffered
// LDS, counted-vmcnt + raw barrier per tile) + round-9 additions to break
// the pipe convoy (r8 counters: MFMA 39% + VALU 41% + LDS ~30% summed to
// ~110% of runtime = zero overlap):
//  (a) intra-tile 4-phase pipeline: phase c prefetches phase c+1's B-frags
//      into the alternate register set BEFORE its MFMA cluster — each wave
//      interleaves {ds_read | MFMA cluster | exp cluster} at fine grain;
//  (b) s_setprio(1) around each 16-MFMA cluster (T5) so the CU scheduler
//      favors the MFMA-phase wave while others run exp/ds_read;
//  (c) swizzled LDS read offsets hoisted out of the tile loop.
// ---------------------------------------------------------------------------
__global__ __launch_bounds__(256, 3) void k_gram(
    const uint16_t* __restrict__ nb, float* __restrict__ sums)
{
  __shared__ alignas(16) uint16_t ldsB[3][64 * DD];   // 3 x 16 KB

  // bijective XCD-chunk swizzle: XCD k gets contiguous ids [k*96,(k+1)*96)
  int bid = (blockIdx.x & 7) * 96 + (blockIdx.x >> 3);
  int job = bid >> 7;          // 128 blocks per job
  int rem = bid & 127;
  int rb = rem >> 2;           // row-block 0..31 (256 rows each)
  int cs = rem & 3;            // col-chunk 0..3  (2048 cols each)
  const int ja[6] = {0, 0, 1, 2, 2, 3};
  const int jb[6] = {1, 0, 1, 3, 2, 3};
  const uint16_t* A = nb + (size_t)ja[job] * NR * DD;
  const uint16_t* B = nb + (size_t)jb[job] * NR * DD;
  float* out = sums + job * NR;

  int tid = threadIdx.x, w = tid >> 6, lane = tid & 63;
  int l15 = lane & 15, lg = lane >> 4;
  int rowBase = rb * 256 + w * 64;

  const char* Bb = (const char*)B;
  char* ldsbase = (char*)&ldsB[0][0];
  int jstart = cs * 2048;

  // hoisted swizzled LDS byte offsets (loop-invariant): phase c, k-slice ks
  int off[4][4];
#pragma unroll
  for (int c = 0; c < 4; ++c) {
    int r = c * 16 + l15;
    int swz = (r & 7) << 4;
#pragma unroll
    for (int ks = 0; ks < 4; ++ks)
      off[c][ks] = (r * 256 + ks * 64 + lg * 16) ^ swz;
  }

  // stage one 64-col B tile (16KB): linear LDS dest, inverse-swizzled global
  // source (rule #21); 4 global_load_lds_dwordx4 per wave.
#define STAGE(dst, jt)                                                        \
  {                                                                           \
    const char* tbase = Bb + (size_t)(jstart + (jt) * 64) * 256;              \
    _Pragma("unroll")                                                         \
    for (int it = 0; it < 4; ++it) {                                          \
      int dbase = w * 4096 + it * 1024;                                       \
      int doff = dbase + lane * 16;                                           \
      int soff = doff ^ (((doff >> 8) & 7) << 4);                             \
      __builtin_amdgcn_global_load_lds(                                       \
          (const __attribute__((address_space(1))) void*)(tbase + soff),      \
          (__attribute__((address_space(3))) void*)((dst) + dbase),           \
          16, 0, 0);                                                          \
    }                                                                         \
  }

  // 4-phase intra-tile pipeline: consume (c&1?bB:bA), prefetch the other.
#define COMPUTE(bufc)                                                         \
  {                                                                           \
    bf16x8 bA[4], bB[4];                                                      \
    _Pragma("unroll")                                                         \
    for (int ks = 0; ks < 4; ++ks)                                            \
      bA[ks] = *(const bf16x8*)((bufc) + off[0][ks]);                         \
    _Pragma("unroll")                                                         \
    for (int c = 0; c < 4; ++c) {                                             \
      if (c < 3) {                                                            \
        if ((c & 1) == 0) {                                                   \
          _Pragma("unroll")                                                   \
          for (int ks = 0; ks < 4; ++ks)                                      \
            bB[ks] = *(const bf16x8*)((bufc) + off[c + 1][ks]);               \
        } else {                                                              \
          _Pragma("unroll")                                                   \
          for (int ks = 0; ks < 4; ++ks)                                      \
            bA[ks] = *(const bf16x8*)((bufc) + off[c + 1][ks]);               \
        }                                                                     \
      }                                                                       \
      f32x4 acc0 = {0.f, 0.f, 0.f, 0.f}, acc1 = {0.f, 0.f, 0.f, 0.f};         \
      f32x4 acc2 = {0.f, 0.f, 0.f, 0.f}, acc3 = {0.f, 0.f, 0.f, 0.f};         \
      __builtin_amdgcn_s_setprio(1);                                          \
      _Pragma("unroll")                                                       \
      for (int ks = 0; ks < 4; ++ks) {                                        \
        const bf16x8 bb = ((c & 1) == 0) ? bA[ks] : bB[ks];                   \
        acc0 = __builtin_amdgcn_mfma_f32_16x16x32_bf16(af[0][ks], bb, acc0, 0, 0, 0); \
        acc1 = __builtin_amdgcn_mfma_f32_16x16x32_bf16(af[1][ks], bb, acc1, 0, 0, 0); \
        acc2 = __builtin_amdgcn_mfma_f32_16x16x32_bf16(af[2][ks], bb, acc2, 0, 0, 0); \
        acc3 = __builtin_amdgcn_mfma_f32_16x16x32_bf16(af[3][ks], bb, acc3, 0, 0, 0); \
      }                                                                       \
      __builtin_amdgcn_s_setprio(0);                                          \
      _Pragma("unroll")                                                       \
      for (int j = 0; j < 4; ++j) {                                           \
        racc[0][j] += EXP2F(acc0[j]);                                         \
        racc[1][j] += EXP2F(acc1[j]);                                         \
        racc[2][j] += EXP2F(acc2[j]);                                         \
        racc[3][j] += EXP2F(acc3[j]);                                         \
      }                                                                       \
    }                                                                         \
  }

  // prologue: stage tile 0; A-frag loads fly under it; one full drain.
  STAGE(ldsbase, 0);

  bf16x8 af[4][4];
#pragma unroll
  for (int m = 0; m < 4; ++m) {
    const uint16_t* ap = A + (size_t)(rowBase + m * 16 + l15) * DD + lg * 8;
#pragma unroll
    for (int ks = 0; ks < 4; ++ks)
      af[m][ks] = *(const bf16x8*)(ap + ks * 32);
  }

  float racc[4][4];
#pragma unroll
  for (int m = 0; m < 4; ++m)
#pragma unroll
    for (int j = 0; j < 4; ++j) racc[m][j] = 0.0f;

  asm volatile("s_waitcnt vmcnt(0)" ::: "memory");
  __builtin_amdgcn_s_barrier();
  __builtin_amdgcn_sched_barrier(0);

  // main loop: counted-vmcnt pipeline, ONE raw barrier per tile
  int cur = 0;
  for (int jt = 0; jt < 31; ++jt) {
    int nxt = cur + 1; if (nxt == 3) nxt = 0;
    STAGE(ldsbase + nxt * 16384, jt + 1);  // 4 loads issued, stay in flight
    __builtin_amdgcn_sched_barrier(0);
    asm volatile("s_waitcnt vmcnt(4)" ::: "memory");  // stage(jt) retired
    __builtin_amdgcn_s_barrier();                     // ...in ALL waves
    __builtin_amdgcn_sched_barrier(0);
    COMPUTE(ldsbase + cur * 16384);
    cur = nxt;
  }
  // epilogue: tile 31
  __builtin_amdgcn_sched_barrier(0);
  asm volatile("s_waitcnt vmcnt(0)" ::: "memory");
  __builtin_amdgcn_s_barrier();
  __builtin_amdgcn_sched_barrier(0);
  COMPUTE(ldsbase + cur * 16384);

  // row-sums: reduce over the 16 lanes (cols) in each lg group
#pragma unroll
  for (int off2 = 1; off2 < 16; off2 <<= 1)
#pragma unroll
    for (int m = 0; m < 4; ++m)
#pragma unroll
      for (int j = 0; j < 4; ++j)
        racc[m][j] += __shfl_xor(racc[m][j], off2, 64);

  if (l15 == 0) {
#pragma unroll
    for (int m = 0; m < 4; ++m)
#pragma unroll
      for (int j = 0; j < 4; ++j)
        atomicAdd(&out[rowBase + m * 16 + lg * 4 + j], racc[m][j]);
  }
#undef STAGE
#undef COMPUTE
}

// ---------------------------------------------------------------------------
// K3: finalize.  16 rows per wave, one atomic per BLOCK (256 total).
// loss += log(s12+s11+p0) + log(s12+s22+p0) - 2*log(p0);  out = loss/4.
// ---------------------------------------------------------------------------
__global__ __launch_bounds__(256) void k_finalize(
    const uint16_t* __restrict__ nb, const float* __restrict__ diag,
    const float* __restrict__ sums, float* __restrict__ out)
{
  __shared__ float part[4];
  int tid = threadIdx.x, w = tid >> 6, lane = tid & 63;
  int waveId = blockIdx.x * 4 + w;        // 0..1023
  float local = 0.0f;

  for (int i = 0; i < 16; ++i) {
    int rowId = waveId * 16 + i;          // 0..16383
    int p = rowId >> 13, r = rowId & (NR - 1);
    const uint16_t* n1 = nb + (size_t)(2 * p) * NR * DD + (size_t)r * DD;
    const uint16_t* n2 = n1 + (size_t)NR * DD;
    uint32_t a = *(const uint32_t*)(n1 + lane * 2);
    uint32_t b = *(const uint32_t*)(n2 + lane * 2);
    float a0 = bf2f((uint16_t)(a & 0xFFFFu)), a1 = bf2f((uint16_t)(a >> 16));
    float b0 = bf2f((uint16_t)(b & 0xFFFFu)), b1 = bf2f((uint16_t)(b >> 16));
    // values pre-scaled by SQK: product is already the exp2 argument
    float p0 = EXP2F(a0 * b0) + EXP2F(a1 * b1);
#pragma unroll
    for (int off = 32; off >= 1; off >>= 1) p0 += __shfl_xor(p0, off, 64);

    if (lane == 0) {
      const float* s12v = sums + (3 * p) * NR;
      const float* s11v = sums + (3 * p + 1) * NR;
      const float* s22v = sums + (3 * p + 2) * NR;
      float e1 = EXP2F(diag[(2 * p) * NR + r]);
      float e2 = EXP2F(diag[(2 * p + 1) * NR + r]);
      float s12 = s12v[r];
      float S1 = s12 + (s11v[r] - e1) + p0;
      float S2 = s12 + (s22v[r] - e2) + p0;
      local += logf(S1) + logf(S2) - 2.0f * logf(p0);
    }
  }
  if (lane == 0) part[w] = local;
  __syncthreads();
  if (tid == 0) {
    float t = part[0] + part[1] + part[2] + part[3];
    atomicAdd(out, 0.25f * t);
  }
}

// ---------------------------------------------------------------------------
extern "C" void kernel_launch(void* const* d_in, const int* in_sizes, int n_in,
                              void* d_out, int out_size, void* d_ws, size_t ws_size,
                              hipStream_t stream) {
  const float* u1 = (const float*)d_in[0];
  const float* u2 = (const float*)d_in[1];
  const float* i1 = (const float*)d_in[2];
  const float* i2 = (const float*)d_in[3];

  // ws layout: 4 bf16 matrices (8 MB) | diag[4][NR] f32 | sums[6][NR] f32
  uint16_t* nb = (uint16_t*)d_ws;
  float* diag = (float*)((char*)d_ws + (size_t)4 * NR * DD * sizeof(uint16_t));
  float* sums = diag + 4 * NR;
  float* out = (float*)d_out;

  k_normalize<<<NR * 4 / 4, 256, 0, stream>>>(u1, u2, i1, i2, nb, diag, sums, out);
  k_gram<<<768, 256, 0, stream>>>(nb, sums);
  k_finalize<<<256, 256, 0, stream>>>(nb, diag, sums, out);
}

// Round 10
// 88.526 us; speedup vs baseline: 1.4748x; 1.4748x over previous
//
#include <hip/hip_runtime.h>
#include <stdint.h>

#define NR 8192
#define DD 128

typedef __attribute__((ext_vector_type(4))) int int32x4;
typedef __attribute__((ext_vector_type(8))) int int32x8;
typedef __attribute__((ext_vector_type(4))) float f32x4;

#ifdef __has_builtin
#if __has_builtin(__builtin_amdgcn_exp2f)
#define EXP2F __builtin_amdgcn_exp2f
#endif
#endif
#ifndef EXP2F
#define EXP2F exp2f
#endif

// exp(10*x) == exp2(x * 10/ln2).  10/ln2 folded into the stored values:
// q = e4m3( sqrt(10/ln2) * normalized ), so every pairwise product (MFMA
// dot, p0 elementwise, diag) is already the exp2 argument.
#define SQK 3.79828255f     // sqrt(10/ln2)
#define SCALE1 0x7F7F7F7F   // e8m0 127 = 2^0 in every byte (opsel-proof)

// ---- OCP e4m3fn software encode (RNE) / decode (exact) --------------------
__device__ __forceinline__ uint32_t enc_e4m3(float x) {
  uint32_t u = __float_as_uint(x);
  uint32_t s = (u >> 31) << 7;
  float ax = fabsf(x);
  if (ax < 0.015625f) {                 // subnormal target: m * 2^-9
    int m = (int)rintf(ax * 512.0f);    // RNE; 0..8
    return (m >= 8) ? (s | (1u << 3)) : (s | (uint32_t)m);
  }
  uint32_t v = u & 0x7FFFFFFFu;
  v += 0x7FFFFu + ((v >> 20) & 1u);     // RNE to 3 mantissa bits
  int e = (int)((v >> 23) & 255u) - 127;
  uint32_t m3 = (v >> 20) & 7u;
  return s | ((uint32_t)(e + 7) << 3) | m3;   // |x| <= ~2 -> no overflow
}
__device__ __forceinline__ float dec_e4m3(uint32_t b) {
  uint32_t s = b >> 7, e = (b >> 3) & 15u, m = b & 7u;
  float v = e ? __uint_as_float(((e + 120u) << 23) | (m << 20))
              : (float)m * 0.001953125f;      // m * 2^-9
  return s ? -v : v;
}

// ---------------------------------------------------------------------------
// K1: row L2-normalize (fp32), emit e4m3 copies scaled by SQK, diag =
// sum(dequant^2) (== the MFMA Gram diagonal).  Zeroes sums and d_out.
// ---------------------------------------------------------------------------
__global__ __launch_bounds__(256) void k_normalize(
    const float* __restrict__ u1, const float* __restrict__ u2,
    const float* __restrict__ i1, const float* __restrict__ i2,
    uint8_t* __restrict__ nb, float* __restrict__ diag,
    float* __restrict__ sums, float* __restrict__ out)
{
  int tid = threadIdx.x;
  int gid = blockIdx.x * 256 + tid;
  if (gid < 6 * NR) sums[gid] = 0.0f;
  if (gid == 0) out[0] = 0.0f;

  int w = tid >> 6, lane = tid & 63;
  int rowId = blockIdx.x * 4 + w;            // 0..32767
  int mi = rowId >> 13, r = rowId & (NR - 1);
  const float* src = (mi == 0) ? u1 : (mi == 1) ? u2 : (mi == 2) ? i1 : i2;
  const float2 v = *(const float2*)(src + (size_t)r * DD + lane * 2);
  float ss = v.x * v.x + v.y * v.y;
#pragma unroll
  for (int off = 32; off >= 1; off >>= 1) ss += __shfl_xor(ss, off, 64);
  float sc = SQK / fmaxf(sqrtf(ss), 1e-12f);
  uint32_t c0 = enc_e4m3(v.x * sc);
  uint32_t c1 = enc_e4m3(v.y * sc);
  uint8_t* dst = nb + (size_t)mi * NR * DD + (size_t)r * DD + lane * 2;
  *(uint16_t*)dst = (uint16_t)(c0 | (c1 << 8));
  float d0 = dec_e4m3(c0), d1 = dec_e4m3(c1);
  float dd = d0 * d0 + d1 * d1;
#pragma unroll
  for (int off = 32; off >= 1; off >>= 1) dd += __shfl_xor(dd, off, 64);
  if (lane == 0) diag[rowId] = dd;
}

// ---------------------------------------------------------------------------
// K2: Gram row-sums, MX-fp8.  r8 outer structure (768 blocks, 6 full Grams,
// triple-buffered LDS, counted-vmcnt + raw barrier per tile) with:
//   - e4m3 data: tile = 64 cols x 128 B = 8 KB (2 gload_lds/wave/tile)
//   - one mfma_scale_f32_16x16x128_f8f6f4 per (m,c): K=128 in ONE MFMA,
//     scales = 2^0.  MFMA cycles ~2.2x fewer, LDS bytes 2x fewer.
//   - XOR swizzle byte^=((row&7)<<4), balanced 8-lanes/16B-slot on reads.
// K-contraction is position-paired, so A and B using the same lane->k map
// (row=lane&15, k=lg*32..+32) is correct regardless of HW's internal order.
// ---------------------------------------------------------------------------
__global__ __launch_bounds__(256, 3) void k_gram(
    const uint8_t* __restrict__ nb, float* __restrict__ sums)
{
  __shared__ alignas(16) uint8_t ldsB[3][64 * DD];   // 3 x 8 KB

  // bijective XCD-chunk swizzle: XCD k gets contiguous ids [k*96,(k+1)*96)
  int bid = (blockIdx.x & 7) * 96 + (blockIdx.x >> 3);
  int job = bid >> 7;          // 128 blocks per job
  int rem = bid & 127;
  int rb = rem >> 2;           // row-block 0..31 (256 rows each)
  int cs = rem & 3;            // col-chunk 0..3  (2048 cols each)
  const int ja[6] = {0, 0, 1, 2, 2, 3};
  const int jb[6] = {1, 0, 1, 3, 2, 3};
  const uint8_t* A = nb + (size_t)ja[job] * NR * DD;
  const uint8_t* B = nb + (size_t)jb[job] * NR * DD;
  float* out = sums + job * NR;

  int tid = threadIdx.x, w = tid >> 6, lane = tid & 63;
  int l15 = lane & 15, lg = lane >> 4;
  int rowBase = rb * 256 + w * 64;

  const char* Bb = (const char*)B;
  char* ldsbase = (char*)&ldsB[0][0];
  int jstart = cs * 2048;

  // stage one 64-col tile (8KB): linear LDS dest, inverse-swizzled source
  // (rule #21).  2 x global_load_lds_dwordx4 per wave.
#define STAGE(dst, jt)                                                        \
  {                                                                           \
    const char* tbase = Bb + (size_t)(jstart + (jt) * 64) * 128;              \
    _Pragma("unroll")                                                         \
    for (int it = 0; it < 2; ++it) {                                          \
      int dbase = it * 4096 + w * 1024;                                       \
      int doff = dbase + lane * 16;                                           \
      int soff = doff ^ (((doff >> 7) & 7) << 4);                             \
      __builtin_amdgcn_global_load_lds(                                       \
          (const __attribute__((address_space(1))) void*)(tbase + soff),      \
          (__attribute__((address_space(3))) void*)((dst) + dbase),           \
          16, 0, 0);                                                          \
    }                                                                         \
  }

#define COMPUTE(bufc)                                                         \
  {                                                                           \
    _Pragma("unroll")                                                         \
    for (int c = 0; c < 4; ++c) {                                             \
      int r = c * 16 + l15;                                                   \
      int base = r * 128 + lg * 32;                                           \
      int swz = (r & 7) << 4;                                                 \
      int32x4 blo = *(const int32x4*)((bufc) + (base ^ swz));                 \
      int32x4 bhi = *(const int32x4*)((bufc) + ((base + 16) ^ swz));          \
      int32x8 b8 = __builtin_shufflevector(blo, bhi, 0, 1, 2, 3, 4, 5, 6, 7); \
      _Pragma("unroll")                                                       \
      for (int m = 0; m < 4; ++m) {                                           \
        f32x4 acc = {0.0f, 0.0f, 0.0f, 0.0f};                                 \
        acc = __builtin_amdgcn_mfma_scale_f32_16x16x128_f8f6f4(               \
            af[m], b8, acc, 0, 0, 0, SCALE1, 0, SCALE1);                      \
        _Pragma("unroll")                                                     \
        for (int j = 0; j < 4; ++j)                                           \
          racc[m][j] += EXP2F(acc[j]);                                        \
      }                                                                       \
    }                                                                         \
  }

  // prologue: stage tile 0; A-frag loads fly under it; one full drain.
  STAGE(ldsbase, 0);

  // A fragments: row rowBase+m*16+l15, k-bytes [lg*32, lg*32+32)
  int32x8 af[4];
#pragma unroll
  for (int m = 0; m < 4; ++m)
    af[m] = *(const int32x8*)(A + (size_t)(rowBase + m * 16 + l15) * DD + lg * 32);

  float racc[4][4];
#pragma unroll
  for (int m = 0; m < 4; ++m)
#pragma unroll
    for (int j = 0; j < 4; ++j) racc[m][j] = 0.0f;

  asm volatile("s_waitcnt vmcnt(0)" ::: "memory");
  __builtin_amdgcn_s_barrier();
  __builtin_amdgcn_sched_barrier(0);

  // main loop: counted-vmcnt pipeline, ONE raw barrier per tile
  int cur = 0;
  for (int jt = 0; jt < 31; ++jt) {
    int nxt = cur + 1; if (nxt == 3) nxt = 0;
    STAGE(ldsbase + nxt * 8192, jt + 1);   // 2 loads issued, stay in flight
    __builtin_amdgcn_sched_barrier(0);
    asm volatile("s_waitcnt vmcnt(2)" ::: "memory");  // stage(jt) retired
    __builtin_amdgcn_s_barrier();                     // ...in ALL waves
    __builtin_amdgcn_sched_barrier(0);
    COMPUTE(ldsbase + cur * 8192);
    cur = nxt;
  }
  // epilogue: tile 31
  __builtin_amdgcn_sched_barrier(0);
  asm volatile("s_waitcnt vmcnt(0)" ::: "memory");
  __builtin_amdgcn_s_barrier();
  __builtin_amdgcn_sched_barrier(0);
  COMPUTE(ldsbase + cur * 8192);

  // row-sums: reduce over the 16 lanes (cols) in each lg group
#pragma unroll
  for (int off = 1; off < 16; off <<= 1)
#pragma unroll
    for (int m = 0; m < 4; ++m)
#pragma unroll
      for (int j = 0; j < 4; ++j)
        racc[m][j] += __shfl_xor(racc[m][j], off, 64);

  if (l15 == 0) {
#pragma unroll
    for (int m = 0; m < 4; ++m)
#pragma unroll
      for (int j = 0; j < 4; ++j)
        atomicAdd(&out[rowBase + m * 16 + lg * 4 + j], racc[m][j]);
  }
#undef STAGE
#undef COMPUTE
}

// ---------------------------------------------------------------------------
// K3: finalize.  16 rows per wave, one atomic per BLOCK (256 total).
// loss += log(s12+s11+p0) + log(s12+s22+p0) - 2*log(p0);  out = loss/4.
// ---------------------------------------------------------------------------
__global__ __launch_bounds__(256) void k_finalize(
    const uint8_t* __restrict__ nb, const float* __restrict__ diag,
    const float* __restrict__ sums, float* __restrict__ out)
{
  __shared__ float part[4];
  int tid = threadIdx.x, w = tid >> 6, lane = tid & 63;
  int waveId = blockIdx.x * 4 + w;        // 0..1023
  float local = 0.0f;

  for (int i = 0; i < 16; ++i) {
    int rowId = waveId * 16 + i;          // 0..16383
    int p = rowId >> 13, r = rowId & (NR - 1);
    const uint8_t* n1 = nb + (size_t)(2 * p) * NR * DD + (size_t)r * DD;
    const uint8_t* n2 = n1 + (size_t)NR * DD;
    uint32_t a = *(const uint16_t*)(n1 + lane * 2);
    uint32_t b = *(const uint16_t*)(n2 + lane * 2);
    float a0 = dec_e4m3(a & 0xFFu), a1 = dec_e4m3(a >> 8);
    float b0 = dec_e4m3(b & 0xFFu), b1 = dec_e4m3(b >> 8);
    // values pre-scaled by SQK: product is already the exp2 argument
    float p0 = EXP2F(a0 * b0) + EXP2F(a1 * b1);
#pragma unroll
    for (int off = 32; off >= 1; off >>= 1) p0 += __shfl_xor(p0, off, 64);

    if (lane == 0) {
      const float* s12v = sums + (3 * p) * NR;
      const float* s11v = sums + (3 * p + 1) * NR;
      const float* s22v = sums + (3 * p + 2) * NR;
      float e1 = EXP2F(diag[(2 * p) * NR + r]);
      float e2 = EXP2F(diag[(2 * p + 1) * NR + r]);
      float s12 = s12v[r];
      float S1 = s12 + (s11v[r] - e1) + p0;
      float S2 = s12 + (s22v[r] - e2) + p0;
      local += logf(S1) + logf(S2) - 2.0f * logf(p0);
    }
  }
  if (lane == 0) part[w] = local;
  __syncthreads();
  if (tid == 0) {
    float t = part[0] + part[1] + part[2] + part[3];
    atomicAdd(out, 0.25f * t);
  }
}

// ---------------------------------------------------------------------------
extern "C" void kernel_launch(void* const* d_in, const int* in_sizes, int n_in,
                              void* d_out, int out_size, void* d_ws, size_t ws_size,
                              hipStream_t stream) {
  const float* u1 = (const float*)d_in[0];
  const float* u2 = (const float*)d_in[1];
  const float* i1 = (const float*)d_in[2];
  const float* i2 = (const float*)d_in[3];

  // ws layout: 4 e4m3 matrices (4 MB) | diag[4][NR] f32 | sums[6][NR] f32
  uint8_t* nb = (uint8_t*)d_ws;
  float* diag = (float*)((char*)d_ws + (size_t)4 * NR * DD);
  float* sums = diag + 4 * NR;
  float* out = (float*)d_out;

  k_normalize<<<NR * 4 / 4, 256, 0, stream>>>(u1, u2, i1, i2, nb, diag, sums, out);
  k_gram<<<768, 256, 0, stream>>>(nb, sums);
  k_finalize<<<256, 256, 0, stream>>>(nb, diag, sums, out);
}